// Round 2
// baseline (10.842 us; speedup 1.0000x reference)
//
#include <hip/hip_runtime.h>

// Quanvolution collapses analytically:
//   z_i = cos(params[i]) * cos(theta_i)   (theta = 2x2 patch values, row-major)
//   out = [z1*z2*z3, z0*z1, z0*z1*z2, z0*z1*z2*z3]
// Product state => probs factorize; CNOT ring is a bit permutation with
// final bits (b1^b2^b3, b0^b1, b0^b1^b2, b0^b1^b2^b3); E[(-1)^xor] = prod z_i.
//
// This version: 2 adjacent patches per thread -> float4 loads (16B/lane) on
// both row streams, 2x float4 contiguous stores, half the threads.

__global__ __launch_bounds__(256) void quanv_kernel2(
    const float* __restrict__ x,      // [B,1,28,28]
    const float* __restrict__ params, // [4]
    float* __restrict__ out,          // [B,196*4]
    int N2)                           // B*98 patch-pairs
{
    int idx = blockIdx.x * blockDim.x + threadIdx.x;
    if (idx >= N2) return;

    int b   = idx / 98;
    int rem = idx - b * 98;
    int pr  = rem / 7;
    int pcq = rem - pr * 7;          // pair index 0..6 -> cols 4*pcq..4*pcq+3

    const float* base = x + b * 784 + (2 * pr) * 28 + 4 * pcq;
    float4 r0 = *reinterpret_cast<const float4*>(base);       // t0a t1a t0b t1b
    float4 r1 = *reinterpret_cast<const float4*>(base + 28);  // t2a t3a t2b t3b

    float cp0 = __cosf(params[0]);
    float cp1 = __cosf(params[1]);
    float cp2 = __cosf(params[2]);
    float cp3 = __cosf(params[3]);

    // patch A
    float z0 = cp0 * __cosf(r0.x);
    float z1 = cp1 * __cosf(r0.y);
    float z2 = cp2 * __cosf(r1.x);
    float z3 = cp3 * __cosf(r1.y);
    float4 oa;
    oa.y = z0 * z1;
    oa.x = z1 * z2 * z3;
    oa.z = oa.y * z2;
    oa.w = oa.z * z3;

    // patch B
    float w0 = cp0 * __cosf(r0.z);
    float w1 = cp1 * __cosf(r0.w);
    float w2 = cp2 * __cosf(r1.z);
    float w3 = cp3 * __cosf(r1.w);
    float4 ob;
    ob.y = w0 * w1;
    ob.x = w1 * w2 * w3;
    ob.z = ob.y * w2;
    ob.w = ob.z * w3;

    float* o = out + (size_t)(b * 784 + pr * 56 + 8 * pcq);
    reinterpret_cast<float4*>(o)[0] = oa;
    reinterpret_cast<float4*>(o)[1] = ob;
}

extern "C" void kernel_launch(void* const* d_in, const int* in_sizes, int n_in,
                              void* d_out, int out_size, void* d_ws, size_t ws_size,
                              hipStream_t stream) {
    const float* x      = (const float*)d_in[0];
    const float* params = (const float*)d_in[1];
    float* out          = (float*)d_out;

    int B  = in_sizes[0] / 784;  // 4096
    int N2 = B * 98;             // patch-pairs
    int block = 256;
    int grid  = (N2 + block - 1) / block;
    quanv_kernel2<<<grid, block, 0, stream>>>(x, params, out, N2);
}

// Round 4
// 10.384 us; speedup vs baseline: 1.0441x; 1.0441x over previous
//
#include <hip/hip_runtime.h>

// Quanvolution collapses analytically:
//   z_i = cos(params[i]) * cos(theta_i)   (theta = 2x2 patch values, row-major)
//   out = [z1*z2*z3, z0*z1, z0*z1*z2, z0*z1*z2*z3]
// Product state => probs factorize; CNOT ring is a bit permutation with
// final bits (b1^b2^b3, b0^b1, b0^b1^b2, b0^b1^b2^b3); E[(-1)^xor] = prod z_i.
//
// Round-1 structure (1 patch/thread, 8B loads, 16B store) + nontemporal
// load/store via clang ext_vector types (HIP_vector_type is a class and
// __builtin_nontemporal_* rejects it).

typedef float v2f __attribute__((ext_vector_type(2)));
typedef float v4f __attribute__((ext_vector_type(4)));

__global__ __launch_bounds__(256) void quanv_kernel(
    const float* __restrict__ x,      // [B,1,28,28]
    const float* __restrict__ params, // [4]
    float* __restrict__ out,          // [B,196*4]
    int N)                            // B*196 patches
{
    int idx = blockIdx.x * blockDim.x + threadIdx.x;
    if (idx >= N) return;

    int b     = idx / 196;
    int patch = idx - b * 196;
    int pr    = patch / 14;
    int pc    = patch - pr * 14;

    const float* base = x + b * 784 + (2 * pr) * 28 + 2 * pc;
    v2f r0 = __builtin_nontemporal_load(reinterpret_cast<const v2f*>(base));
    v2f r1 = __builtin_nontemporal_load(reinterpret_cast<const v2f*>(base + 28));

    float cp0 = __cosf(params[0]);
    float cp1 = __cosf(params[1]);
    float cp2 = __cosf(params[2]);
    float cp3 = __cosf(params[3]);

    float z0 = cp0 * __cosf(r0.x);
    float z1 = cp1 * __cosf(r0.y);
    float z2 = cp2 * __cosf(r1.x);
    float z3 = cp3 * __cosf(r1.y);

    v4f o;
    o.y = z0 * z1;        // <Z1>
    o.x = z1 * z2 * z3;   // <Z0>
    o.z = o.y * z2;       // <Z2>
    o.w = o.z * z3;       // <Z3>
    __builtin_nontemporal_store(o, reinterpret_cast<v4f*>(out + (size_t)idx * 4));
}

extern "C" void kernel_launch(void* const* d_in, const int* in_sizes, int n_in,
                              void* d_out, int out_size, void* d_ws, size_t ws_size,
                              hipStream_t stream) {
    const float* x      = (const float*)d_in[0];
    const float* params = (const float*)d_in[1];
    float* out          = (float*)d_out;

    int B = in_sizes[0] / 784;   // 4096
    int N = B * 196;             // patches
    int block = 256;
    int grid  = (N + block - 1) / block;
    quanv_kernel<<<grid, block, 0, stream>>>(x, params, out, N);
}